// Round 16
// baseline (45.652 us; speedup 1.0000x reference)
//
#include <hip/hip_runtime.h>
#include <hip/hip_bf16.h>

#define NB 4
#define NT 2048
#define DM 1024
#define DH 64
#define CHUNK3 2          // KV chunk in units of 128-key tiles
#define SLOTS 8

typedef __attribute__((ext_vector_type(8))) short bf16x8;
typedef __attribute__((ext_vector_type(4))) float f32x4;
typedef unsigned short u16;
typedef unsigned int u32;

static __device__ __forceinline__ u16 f2b(float f) {
    __hip_bfloat16 h = __float2bfloat16(f);
    return __builtin_bit_cast(u16, h);
}
static __device__ __forceinline__ float b2f(u16 h) {
    return __builtin_bit_cast(float, (u32)h << 16);
}
// global -> LDS DMA, 16B per lane. lds ptr must be wave-uniform (HW adds lane*16).
static __device__ __forceinline__ void gld16(const void* g, void* l) {
    __builtin_amdgcn_global_load_lds((const __attribute__((address_space(1))) void*)g,
                                     (__attribute__((address_space(3))) void*)l, 16, 0, 0);
}
#define BAR() __builtin_amdgcn_s_barrier()
#define SBAR() __builtin_amdgcn_sched_barrier(0)

// ---------------------------------------------------------------------------
// Wt[which][d][k] bf16 <- W[k][d] fp32, via LDS transpose. grid (16, 3)
// ---------------------------------------------------------------------------
__global__ __launch_bounds__(256) void wt_conv(
    const float* __restrict__ WQ, const float* __restrict__ WK,
    const float* __restrict__ WV, u16* __restrict__ wt)
{
    __shared__ u16 tl[64][68];
    const int which = blockIdx.y, kt = blockIdx.x;
    const float* W = (which == 0) ? WQ : (which == 1) ? WK : WV;
    #pragma unroll
    for (int i = 0; i < 4; ++i) {
        int r = (threadIdx.x >> 4) + i * 16;         // k-local
        int c = (threadIdx.x & 15) * 4;              // d
        float4 v = *(const float4*)&W[(size_t)(kt * 64 + r) * DH + c];
        tl[r][c] = f2b(v.x); tl[r][c + 1] = f2b(v.y);
        tl[r][c + 2] = f2b(v.z); tl[r][c + 3] = f2b(v.w);
    }
    __syncthreads();
    int d = threadIdx.x >> 2, kc = (threadIdx.x & 3) * 16;
    u16 buf[16];
    #pragma unroll
    for (int j = 0; j < 16; ++j) buf[j] = tl[kc + j][d];
    u16* dst = wt + which * 65536 + d * 1024 + kt * 64 + kc;
    *(uint4*)dst = *(uint4*)&buf[0];
    *(uint4*)(dst + 8) = *(uint4*)&buf[8];
}

// ---------------------------------------------------------------------------
// QKV GEMM, bf16-x staging (R15 body). grid (128, 3).
// ---------------------------------------------------------------------------
__global__ __launch_bounds__(256) void qkv_gemm(
    const float* __restrict__ x, const u16* __restrict__ wt,
    u16* __restrict__ Qb, u16* __restrict__ Kb, u16* __restrict__ Vt)
{
    __shared__ u16 xbuf[2][4096];     // [64 r][64 k] bf16, rows 128B, ^((r&7)<<4)
    __shared__ u16 wsm[2][4096];      // same layout
    const int tid = threadIdx.x, lane = tid & 63, w = tid >> 6;
    const int l15 = lane & 15, g = lane >> 4;
    const int row0 = blockIdx.x * 64;
    const int which = blockIdx.y;
    const u16* Wg = wt + which * 65536;

    const int xr_ = tid >> 2, xc4 = tid & 3;
    const float* xsrc = x + (size_t)(row0 + xr_) * DM + xc4 * 16;
    const u32 xsw = (u32)((xr_ & 7) << 4);
    const u32 xa0 = (u32)(xr_ * 128 + xc4 * 32) ^ xsw;
    const u32 xa1 = (u32)(xr_ * 128 + xc4 * 32 + 16) ^ xsw;

    f32x4 xv[4];
    auto xload = [&](int kt) {
        const float* p = xsrc + kt * 64;
        xv[0] = *(const f32x4*)(p);
        xv[1] = *(const f32x4*)(p + 4);
        xv[2] = *(const f32x4*)(p + 8);
        xv[3] = *(const f32x4*)(p + 12);
    };
    auto stageW = [&](int kt, int bi) {
        #pragma unroll
        for (int i = 0; i < 2; ++i) {
            u32 D = (u32)(w * 2048 + i * 1024 + lane * 16);
            u32 r = D >> 7, c = D & 127;
            u32 cs = c ^ ((r & 7) << 4);
            gld16(Wg + (size_t)r * 1024 + kt * 64 + (cs >> 1),
                  (char*)&wsm[bi][0] + w * 2048 + i * 1024);
        }
    };

    f32x4 acc[4];
    #pragma unroll
    for (int i = 0; i < 4; ++i) acc[i] = {0.f, 0.f, 0.f, 0.f};

    xload(0);
    stageW(0, 0);
    const int arow = w * 16 + l15;
    const u32 asw = (u32)((arow & 7) << 4);

    #pragma unroll
    for (int kt = 0; kt < 16; ++kt) {
        const int cur = kt & 1;
        asm volatile("s_waitcnt vmcnt(2)" ::: "memory");   // x(kt) regs ready
        {
            u16 tmp[16];
            #pragma unroll
            for (int i = 0; i < 4; ++i)
                #pragma unroll
                for (int j = 0; j < 4; ++j) tmp[i * 4 + j] = f2b(xv[i][j]);
            *(uint4*)((char*)&xbuf[cur][0] + xa0) = *(uint4*)&tmp[0];
            *(uint4*)((char*)&xbuf[cur][0] + xa1) = *(uint4*)&tmp[8];
        }
        if (kt < 15) {
            xload(kt + 1);
            stageW(kt + 1, cur ^ 1);
            asm volatile("s_waitcnt vmcnt(6)" ::: "memory");   // W(kt) landed
        } else {
            asm volatile("s_waitcnt vmcnt(0)" ::: "memory");
        }
        asm volatile("s_waitcnt lgkmcnt(0)" ::: "memory");     // x writes done
        BAR();                                    // publish buf[cur]
        SBAR();
        const char* xb = (const char*)&xbuf[cur][0];
        const char* wb = (const char*)&wsm[cur][0];
        #pragma unroll
        for (int ks = 0; ks < 2; ++ks) {
            bf16x8 afrag = *(const bf16x8*)(xb + ((u32)(arow * 128 + ks * 64 + g * 16) ^ asw));
            __builtin_amdgcn_s_setprio(1);
            #pragma unroll
            for (int nt = 0; nt < 4; ++nt) {
                int brow = nt * 16 + l15;
                u32 bb = (u32)(brow * 128 + ks * 64 + g * 16);
                bf16x8 bfrag = *(const bf16x8*)(wb + (bb ^ ((brow & 7) << 4)));
                acc[nt] = __builtin_amdgcn_mfma_f32_16x16x32_bf16(afrag, bfrag, acc[nt], 0, 0, 0);
            }
            __builtin_amdgcn_s_setprio(0);
        }
        BAR();                                    // release buf[cur]
    }
    #pragma unroll
    for (int nt = 0; nt < 4; ++nt) {
        int dcol = nt * 16 + l15;
        #pragma unroll
        for (int r = 0; r < 4; ++r) {
            int row = row0 + w * 16 + g * 4 + r;
            float v = acc[nt][r];
            if (which == 0)      Qb[(size_t)row * DH + dcol] = f2b(v * 0.125f);
            else if (which == 1) Kb[(size_t)row * DH + dcol] = f2b(v);
            else { int bb2 = row >> 11, t = row & 2047;
                   Vt[(size_t)bb2 * DH * NT + (size_t)dcol * NT + t] = f2b(v); }
        }
    }
}

// ---------------------------------------------------------------------------
// Flash attention, KVBLK=128, SINGLE-buffered (48 KB LDS -> 3 blocks/CU),
// CHUNK3=2 (gx=144, 576 blocks, all co-resident, max chain 2 tiles).
// Serial stage -> vmcnt(0) -> compute per tile; TLP (12 waves/CU) hides
// the staging latency. Swapped-operand in-register softmax (R14 body).
// ---------------------------------------------------------------------------
__global__ __launch_bounds__(256) void attn(
    const u16* __restrict__ Qb, const u16* __restrict__ Kb,
    const u16* __restrict__ Vt, u16* __restrict__ pOt, float* __restrict__ pml)
{
    __shared__ u16 k_lds[8192];       // 16 KB: [128 j][64 d], rows 128B swz
    __shared__ u16 v_lds[8192];       // 16 KB: [64 d][128 j], rows 256B swz
    __shared__ f32x4 p_lds[4][256];   // 16 KB per-wave P repack

    const int tid = threadIdx.x, lane = tid & 63, w = tid >> 6;
    const int l15 = lane & 15, g = lane >> 4;
    const int b = blockIdx.y;

    // decode blockIdx.x -> (qb, chunk)
    int flat = blockIdx.x, qb = 0, nc, nt128;
    for (;;) {
        nt128 = (qb + 2) >> 1;
        nc = (nt128 + CHUNK3 - 1) / CHUNK3;
        if (flat < nc) break;
        flat -= nc; ++qb;
    }
    const int chunk = flat;
    const int t0 = chunk * CHUNK3;
    const int t1 = min(t0 + CHUNK3, nt128);
    const int tD = nt128 - 1;
    const int delta = qb * 64 - tD * 128;         // 0 (even qb) or 64 (odd)
    const int q0 = qb * 64;

    const u16* Qg = Qb + ((size_t)b * NT + q0 + w * 16) * DH;
    const u16* Kg = Kb + (size_t)b * NT * DH;
    const u16* Vg = Vt + (size_t)b * DH * NT;

    auto stage = [&](int t) {
        const int j0 = t * 128;
        #pragma unroll
        for (int i = 0; i < 4; ++i) {
            u32 D = (u32)(w * 4096 + i * 1024 + lane * 16);
            {   // K: [128 r][64 d], rows 128B
                u32 r = D >> 7, c = D & 127;
                u32 cs = c ^ ((r & 7) << 4);
                gld16(Kg + (size_t)(j0 + r) * DH + (cs >> 1),
                      (char*)&k_lds[0] + w * 4096 + i * 1024);
            }
            {   // V: [64 d][128 j], rows 256B
                u32 r = D >> 8, c = D & 255;
                u32 cs = c ^ ((r & 15) << 4);
                gld16(Vg + (size_t)r * NT + j0 + (cs >> 1),
                      (char*)&v_lds[0] + w * 4096 + i * 1024);
            }
        }
    };

    // Q fragment (B-operand): col=l15 -> q = q0 + w*16 + l15, k over d
    bf16x8 qf[2];
    qf[0] = *(const bf16x8*)(Qg + l15 * DH + g * 8);
    qf[1] = *(const bf16x8*)(Qg + l15 * DH + 32 + g * 8);

    float m_run = -INFINITY, l_run = 0.f;
    f32x4 oacc[4];                    // O^T: d = nt*16+g*4+r, q = w*16+l15
    #pragma unroll
    for (int nt = 0; nt < 4; ++nt) oacc[nt] = {0.f, 0.f, 0.f, 0.f};

    char* pw = (char*)&p_lds[w][0];
    const u32 pswz = (u32)((l15 & 15) << 4);
    const int q_local = w * 16 + l15;

    for (int t = t0; t < t1; ++t) {
        stage(t);
        asm volatile("s_waitcnt vmcnt(0)" ::: "memory");
        BAR();                                    // publish tile
        SBAR();
        const char* kb = (const char*)&k_lds[0];
        const char* vb = (const char*)&v_lds[0];

        // ---- QK^T swapped: sacc[f][r] = S[j = f*16+g*4+r][q], f=0..7 ----
        f32x4 sacc[8];
        #pragma unroll
        for (int f = 0; f < 8; ++f) sacc[f] = {0.f, 0.f, 0.f, 0.f};
        __builtin_amdgcn_s_setprio(1);
        #pragma unroll
        for (int ks = 0; ks < 2; ++ks) {
            #pragma unroll
            for (int f = 0; f < 8; ++f) {
                int arow = f * 16 + l15;          // j row in tile
                u32 aa = (u32)(arow * 128 + ks * 64 + g * 16);
                bf16x8 kf = *(const bf16x8*)(kb + (aa ^ ((arow & 7) << 4)));
                sacc[f] = __builtin_amdgcn_mfma_f32_16x16x32_bf16(kf, qf[ks], sacc[f], 0, 0, 0);
            }
        }
        __builtin_amdgcn_s_setprio(0);
        if (t == tD) {  // causal mask on the last tile only
            #pragma unroll
            for (int f = 0; f < 8; ++f)
                #pragma unroll
                for (int r = 0; r < 4; ++r)
                    if (f * 16 + g * 4 + r > delta + q_local) sacc[f][r] = -1e30f;
        }
        // ---- online softmax: 32 values/lane + xor16/xor32 ----
        float mx = -INFINITY;
        #pragma unroll
        for (int f = 0; f < 8; ++f) {
            float a = fmaxf(fmaxf(sacc[f][0], sacc[f][1]),
                            fmaxf(sacc[f][2], sacc[f][3]));
            mx = fmaxf(mx, a);
        }
        mx = fmaxf(mx, __shfl_xor(mx, 16));
        mx = fmaxf(mx, __shfl_xor(mx, 32));
        const float m_new = fmaxf(m_run, mx);
        const float alpha = __expf(m_run - m_new);
        float p[8][4];
        float ps = 0.f;
        #pragma unroll
        for (int f = 0; f < 8; ++f)
            #pragma unroll
            for (int r = 0; r < 4; ++r) {
                float pv = __expf(sacc[f][r] - m_new);
                p[f][r] = pv; ps += pv;
            }
        ps += __shfl_xor(ps, 16);
        ps += __shfl_xor(ps, 32);
        l_run = l_run * alpha + ps;
        m_run = m_new;
        #pragma unroll
        for (int nt = 0; nt < 4; ++nt)
            #pragma unroll
            for (int r = 0; r < 4; ++r) oacc[nt][r] *= alpha;

        // ---- P^T repack via per-wave LDS (same-wave, no barrier) ----
        #pragma unroll
        for (int f = 0; f < 8; ++f) {
            uint2 pk;
            pk.x = (u32)f2b(p[f][0]) | ((u32)f2b(p[f][1]) << 16);
            pk.y = (u32)f2b(p[f][2]) | ((u32)f2b(p[f][3]) << 16);
            u32 a = (u32)(l15 * 256 + f * 32 + g * 8) ^ pswz;
            *(uint2*)(pw + a) = pk;
        }
        bf16x8 pb_[4];
        #pragma unroll
        for (int ksj = 0; ksj < 4; ++ksj)
            pb_[ksj] = *(const bf16x8*)(pw + ((u32)(l15 * 256 + ksj * 64 + g * 16) ^ pswz));

        // ---- PV swapped: oacc[nt] += V[d][j] @ P^T[j][q], j = 0..127 ----
        __builtin_amdgcn_s_setprio(1);
        #pragma unroll
        for (int ksj = 0; ksj < 4; ++ksj) {
            #pragma unroll
            for (int nt = 0; nt < 4; ++nt) {
                int arow = nt * 16 + l15;          // d row
                u32 aa = (u32)(arow * 256 + ksj * 64 + g * 16);
                bf16x8 vf = *(const bf16x8*)(vb + (aa ^ ((arow & 15) << 4)));
                oacc[nt] = __builtin_amdgcn_mfma_f32_16x16x32_bf16(vf, pb_[ksj], oacc[nt], 0, 0, 0);
            }
        }
        __builtin_amdgcn_s_setprio(0);
        BAR();                                    // release tile (before overwrite)
    }

    // write partials: O^T [d][q] bf16 (coalesced in l15), m/l per q
    const int slot = (b * 32 + qb) * SLOTS + chunk;
    u16* Op = pOt + (size_t)slot * 4096;
    #pragma unroll
    for (int nt = 0; nt < 4; ++nt)
        #pragma unroll
        for (int r = 0; r < 4; ++r)
            Op[(nt * 16 + g * 4 + r) * 64 + w * 16 + l15] = f2b(oacc[nt][r]);
    if (g == 0) {
        float* mlp = pml + (size_t)slot * 128;
        mlp[(w * 16 + l15) * 2]     = m_run;
        mlp[(w * 16 + l15) * 2 + 1] = l_run;
    }
}

// ---------------------------------------------------------------------------
// Merge <=SLOTS transposed partials per (b,qb); LDS transpose; fp32 out [q][d].
// grid = NB*32 blocks. nc matches attn decode.
// ---------------------------------------------------------------------------
__global__ __launch_bounds__(256) void merge(
    const u16* __restrict__ pOt, const float* __restrict__ pml,
    float* __restrict__ out)
{
    __shared__ float tl[64][65];
    const int bq = blockIdx.x;             // b*32 + qb
    const int b = bq >> 5, qb = bq & 31;
    const int nt128 = (qb + 2) >> 1;
    const int nc = (nt128 + CHUNK3 - 1) / CHUNK3;
    const int base = bq * SLOTS;
    const int q = threadIdx.x & 63, ds = threadIdx.x >> 6;

    float m = -INFINITY;
    for (int c = 0; c < nc; ++c)
        m = fmaxf(m, pml[(size_t)(base + c) * 128 + q * 2]);
    float lsum = 0.f;
    float acc[16];
    #pragma unroll
    for (int i = 0; i < 16; ++i) acc[i] = 0.f;
    for (int c = 0; c < nc; ++c) {
        const float mc = pml[(size_t)(base + c) * 128 + q * 2];
        const float lc = pml[(size_t)(base + c) * 128 + q * 2 + 1];
        const float wc = __expf(mc - m);
        lsum += wc * lc;
        const u16* Op = pOt + (size_t)(base + c) * 4096;
        #pragma unroll
        for (int i = 0; i < 16; ++i)
            acc[i] += wc * b2f(Op[(ds * 16 + i) * 64 + q]);
    }
    const float inv = 1.f / lsum;
    #pragma unroll
    for (int i = 0; i < 16; ++i) tl[q][ds * 16 + i] = acc[i] * inv;
    __syncthreads();
    const int q2 = threadIdx.x >> 2, dc = threadIdx.x & 3;
    float* orow = out + ((size_t)b * NT + qb * 64 + q2) * 64 + dc * 16;
    #pragma unroll
    for (int j4 = 0; j4 < 4; ++j4) {
        float4 v = { tl[q2][dc * 16 + j4 * 4 + 0], tl[q2][dc * 16 + j4 * 4 + 1],
                     tl[q2][dc * 16 + j4 * 4 + 2], tl[q2][dc * 16 + j4 * 4 + 3] };
        *(float4*)&orow[j4 * 4] = v;
    }
}

extern "C" void kernel_launch(void* const* d_in, const int* in_sizes, int n_in,
                              void* d_out, int out_size, void* d_ws, size_t ws_size,
                              hipStream_t stream) {
    const float* x  = (const float*)d_in[0];
    const float* WQ = (const float*)d_in[1];
    const float* WK = (const float*)d_in[2];
    const float* WV = (const float*)d_in[3];
    float* out = (float*)d_out;

    char* ws = (char*)d_ws;
    u16*   Qb  = (u16*)ws;                          // 1 MB
    u16*   Kb  = (u16*)(ws + 1048576);              // 1 MB
    u16*   Vt  = (u16*)(ws + 2097152);              // 1 MB
    u16*   Wt  = (u16*)(ws + 3145728);              // 384 KB
    u16*   pOt = (u16*)(ws + 3538944);              // 1024 slots * 8 KB = 8 MB
    float* pml = (float*)(ws + 3538944 + 8388608);  // 512 KB

    // attn grid.x = sum over qb of ceil(((qb+2)>>1)/2) = 144
    wt_conv<<<dim3(16, 3), 256, 0, stream>>>(WQ, WK, WV, Wt);
    qkv_gemm<<<dim3(128, 3), 256, 0, stream>>>(x, Wt, Qb, Kb, Vt);
    attn<<<dim3(144, NB), 256, 0, stream>>>(Qb, Kb, Vt, pOt, pml);
    merge<<<NB * 32, 256, 0, stream>>>(pOt, pml, out);
}

// Round 17
// 40.578 us; speedup vs baseline: 1.1250x; 1.1250x over previous
//
#include <hip/hip_runtime.h>
#include <hip/hip_bf16.h>

#define NB 4
#define NT 2048
#define DM 1024
#define DH 64
#define CHUNK3 3          // KV chunk in units of 128-key tiles
#define SLOTS 6

typedef __attribute__((ext_vector_type(8))) short bf16x8;
typedef __attribute__((ext_vector_type(4))) float f32x4;
typedef unsigned short u16;
typedef unsigned int u32;

static __device__ __forceinline__ u16 f2b(float f) {
    __hip_bfloat16 h = __float2bfloat16(f);
    return __builtin_bit_cast(u16, h);
}
static __device__ __forceinline__ float b2f(u16 h) {
    return __builtin_bit_cast(float, (u32)h << 16);
}
// global -> LDS DMA, 16B per lane. lds ptr must be wave-uniform (HW adds lane*16).
static __device__ __forceinline__ void gld16(const void* g, void* l) {
    __builtin_amdgcn_global_load_lds((const __attribute__((address_space(1))) void*)g,
                                     (__attribute__((address_space(3))) void*)l, 16, 0, 0);
}
#define BAR() __builtin_amdgcn_s_barrier()
#define SBAR() __builtin_amdgcn_sched_barrier(0)

// ---------------------------------------------------------------------------
// Wt[which][d][k] bf16 <- W[k][d] fp32, via LDS transpose. grid (16, 3)
// ---------------------------------------------------------------------------
__global__ __launch_bounds__(256) void wt_conv(
    const float* __restrict__ WQ, const float* __restrict__ WK,
    const float* __restrict__ WV, u16* __restrict__ wt)
{
    __shared__ u16 tl[64][68];
    const int which = blockIdx.y, kt = blockIdx.x;
    const float* W = (which == 0) ? WQ : (which == 1) ? WK : WV;
    #pragma unroll
    for (int i = 0; i < 4; ++i) {
        int r = (threadIdx.x >> 4) + i * 16;         // k-local
        int c = (threadIdx.x & 15) * 4;              // d
        float4 v = *(const float4*)&W[(size_t)(kt * 64 + r) * DH + c];
        tl[r][c] = f2b(v.x); tl[r][c + 1] = f2b(v.y);
        tl[r][c + 2] = f2b(v.z); tl[r][c + 3] = f2b(v.w);
    }
    __syncthreads();
    int d = threadIdx.x >> 2, kc = (threadIdx.x & 3) * 16;
    u16 buf[16];
    #pragma unroll
    for (int j = 0; j < 16; ++j) buf[j] = tl[kc + j][d];
    u16* dst = wt + which * 65536 + d * 1024 + kt * 64 + kc;
    *(uint4*)dst = *(uint4*)&buf[0];
    *(uint4*)(dst + 8) = *(uint4*)&buf[8];
}

// ---------------------------------------------------------------------------
// QKV GEMM, bf16-x reg-staging + 3-buffer / SINGLE-barrier-per-step pipeline.
// grid (128, 3). With 3 slots, barrier-skew <= 1 step means the writer of
// slot (kt+1)%3 can only coexist with readers of slot (kt-1)%3 -> distinct
// mod 3 -> no release barrier needed. vmcnt per step: vmcnt(2) [x(kt) regs
// ready; W(kt) may be in flight] -> cvt+ds_write x(kt) -> issue x(kt+1) +
// W(kt+1) -> vmcnt(6) [retires W(kt)] -> lgkmcnt(0) -> BAR -> compute.
// 16 barriers total (was 32). LDS 48 KB -> 3 blocks/CU.
// ---------------------------------------------------------------------------
__global__ __launch_bounds__(256) void qkv_gemm(
    const float* __restrict__ x, const u16* __restrict__ wt,
    u16* __restrict__ Qb, u16* __restrict__ Kb, u16* __restrict__ Vt)
{
    __shared__ u16 xbuf[3][4096];     // [64 r][64 k] bf16, rows 128B, ^((r&7)<<4)
    __shared__ u16 wsm[3][4096];      // same layout
    const int tid = threadIdx.x, lane = tid & 63, w = tid >> 6;
    const int l15 = lane & 15, g = lane >> 4;
    const int row0 = blockIdx.x * 64;
    const int which = blockIdx.y;
    const u16* Wg = wt + which * 65536;

    const int xr_ = tid >> 2, xc4 = tid & 3;
    const float* xsrc = x + (size_t)(row0 + xr_) * DM + xc4 * 16;
    const u32 xsw = (u32)((xr_ & 7) << 4);
    const u32 xa0 = (u32)(xr_ * 128 + xc4 * 32) ^ xsw;
    const u32 xa1 = (u32)(xr_ * 128 + xc4 * 32 + 16) ^ xsw;

    f32x4 xv[4];
    auto xload = [&](int kt) {
        const float* p = xsrc + kt * 64;
        xv[0] = *(const f32x4*)(p);
        xv[1] = *(const f32x4*)(p + 4);
        xv[2] = *(const f32x4*)(p + 8);
        xv[3] = *(const f32x4*)(p + 12);
    };
    auto stageW = [&](int kt, int bi) {
        #pragma unroll
        for (int i = 0; i < 2; ++i) {
            u32 D = (u32)(w * 2048 + i * 1024 + lane * 16);
            u32 r = D >> 7, c = D & 127;
            u32 cs = c ^ ((r & 7) << 4);
            gld16(Wg + (size_t)r * 1024 + kt * 64 + (cs >> 1),
                  (char*)&wsm[bi][0] + w * 2048 + i * 1024);
        }
    };

    f32x4 acc[4];
    #pragma unroll
    for (int i = 0; i < 4; ++i) acc[i] = {0.f, 0.f, 0.f, 0.f};

    xload(0);                                     // 4 VMEM
    stageW(0, 0);                                 // 2 VMEM
    const int arow = w * 16 + l15;
    const u32 asw = (u32)((arow & 7) << 4);

    #pragma unroll
    for (int kt = 0; kt < 16; ++kt) {
        const int cur = kt % 3;
        asm volatile("s_waitcnt vmcnt(2)" ::: "memory");   // x(kt) regs ready
        {   // cvt fp32 -> bf16, swizzled ds_write into slot cur
            u16 tmp[16];
            #pragma unroll
            for (int i = 0; i < 4; ++i)
                #pragma unroll
                for (int j = 0; j < 4; ++j) tmp[i * 4 + j] = f2b(xv[i][j]);
            *(uint4*)((char*)&xbuf[cur][0] + xa0) = *(uint4*)&tmp[0];
            *(uint4*)((char*)&xbuf[cur][0] + xa1) = *(uint4*)&tmp[8];
        }
        if (kt < 15) {
            xload(kt + 1);                        // 4 VMEM
            stageW(kt + 1, (kt + 1) % 3);         // 2 VMEM -> slot (kt+1)%3
            asm volatile("s_waitcnt vmcnt(6)" ::: "memory");   // W(kt) landed
        } else {
            asm volatile("s_waitcnt vmcnt(0)" ::: "memory");
        }
        asm volatile("s_waitcnt lgkmcnt(0)" ::: "memory");     // x writes done
        BAR();                                    // single barrier: publish slot cur
        SBAR();
        const char* xb = (const char*)&xbuf[cur][0];
        const char* wb = (const char*)&wsm[cur][0];
        #pragma unroll
        for (int ks = 0; ks < 2; ++ks) {
            bf16x8 afrag = *(const bf16x8*)(xb + ((u32)(arow * 128 + ks * 64 + g * 16) ^ asw));
            __builtin_amdgcn_s_setprio(1);
            #pragma unroll
            for (int nt = 0; nt < 4; ++nt) {
                int brow = nt * 16 + l15;
                u32 bb = (u32)(brow * 128 + ks * 64 + g * 16);
                bf16x8 bfrag = *(const bf16x8*)(wb + (bb ^ ((brow & 7) << 4)));
                acc[nt] = __builtin_amdgcn_mfma_f32_16x16x32_bf16(afrag, bfrag, acc[nt], 0, 0, 0);
            }
            __builtin_amdgcn_s_setprio(0);
        }
        // no release barrier: 3 slots + skew<=1 step make reuse safe
    }
    // epilogue: C col=l15(+16nt), row=g*4+r
    #pragma unroll
    for (int nt = 0; nt < 4; ++nt) {
        int dcol = nt * 16 + l15;
        #pragma unroll
        for (int r = 0; r < 4; ++r) {
            int row = row0 + w * 16 + g * 4 + r;
            float v = acc[nt][r];
            if (which == 0)      Qb[(size_t)row * DH + dcol] = f2b(v * 0.125f);
            else if (which == 1) Kb[(size_t)row * DH + dcol] = f2b(v);
            else { int bb2 = row >> 11, t = row & 2047;
                   Vt[(size_t)bb2 * DH * NT + (size_t)dcol * NT + t] = f2b(v); }
        }
    }
}

// ---------------------------------------------------------------------------
// Flash attention (R14/R15 champion body, verbatim). KVBLK=128, QBLK=64,
// double-buffered, CHUNK3=3, gx=102.
// ---------------------------------------------------------------------------
__global__ __launch_bounds__(256) void attn(
    const u16* __restrict__ Qb, const u16* __restrict__ Kb,
    const u16* __restrict__ Vt, u16* __restrict__ pOt, float* __restrict__ pml)
{
    __shared__ u16 k_lds[2][8192];    // 2 x 16 KB
    __shared__ u16 v_lds[2][8192];    // 2 x 16 KB
    __shared__ f32x4 p_lds[4][256];   // 4 x 4 KB

    const int tid = threadIdx.x, lane = tid & 63, w = tid >> 6;
    const int l15 = lane & 15, g = lane >> 4;
    const int b = blockIdx.y;

    // decode blockIdx.x -> (qb, chunk)
    int flat = blockIdx.x, qb = 0, nc, nt128;
    for (;;) {
        nt128 = (qb + 2) >> 1;
        nc = (nt128 + CHUNK3 - 1) / CHUNK3;
        if (flat < nc) break;
        flat -= nc; ++qb;
    }
    const int chunk = flat;
    const int t0 = chunk * CHUNK3;
    const int t1 = min(t0 + CHUNK3, nt128);
    const int tD = nt128 - 1;
    const int delta = qb * 64 - tD * 128;         // 0 (even qb) or 64 (odd)
    const int q0 = qb * 64;

    const u16* Qg = Qb + ((size_t)b * NT + q0 + w * 16) * DH;
    const u16* Kg = Kb + (size_t)b * NT * DH;
    const u16* Vg = Vt + (size_t)b * DH * NT;

    auto stage = [&](int t, int bi) {
        const int j0 = t * 128;
        #pragma unroll
        for (int i = 0; i < 4; ++i) {
            u32 D = (u32)(w * 4096 + i * 1024 + lane * 16);
            {   // K: [128 r][64 d], rows 128B
                u32 r = D >> 7, c = D & 127;
                u32 cs = c ^ ((r & 7) << 4);
                gld16(Kg + (size_t)(j0 + r) * DH + (cs >> 1),
                      (char*)&k_lds[bi][0] + w * 4096 + i * 1024);
            }
            {   // V: [64 d][128 j], rows 256B
                u32 r = D >> 8, c = D & 255;
                u32 cs = c ^ ((r & 15) << 4);
                gld16(Vg + (size_t)r * NT + j0 + (cs >> 1),
                      (char*)&v_lds[bi][0] + w * 4096 + i * 1024);
            }
        }
    };
    stage(t0, 0);

    // Q fragment (B-operand): col=l15 -> q = q0 + w*16 + l15, k over d
    bf16x8 qf[2];
    qf[0] = *(const bf16x8*)(Qg + l15 * DH + g * 8);
    qf[1] = *(const bf16x8*)(Qg + l15 * DH + 32 + g * 8);

    float m_run = -INFINITY, l_run = 0.f;
    f32x4 oacc[4];                    // O^T: d = nt*16+g*4+r, q = w*16+l15
    #pragma unroll
    for (int nt = 0; nt < 4; ++nt) oacc[nt] = {0.f, 0.f, 0.f, 0.f};

    char* pw = (char*)&p_lds[w][0];
    const u32 pswz = (u32)((l15 & 15) << 4);
    const int q_local = w * 16 + l15;

    for (int t = t0; t < t1; ++t) {
        const int cur = (t - t0) & 1;
        if (t + 1 < t1) {
            stage(t + 1, cur ^ 1);
            asm volatile("s_waitcnt vmcnt(8)" ::: "memory");
        } else {
            asm volatile("s_waitcnt vmcnt(0)" ::: "memory");
        }
        BAR();                                    // publish cur
        SBAR();
        const char* kb = (const char*)&k_lds[cur][0];
        const char* vb = (const char*)&v_lds[cur][0];

        // ---- QK^T swapped: sacc[f][r] = S[j = f*16+g*4+r][q], f=0..7 ----
        f32x4 sacc[8];
        #pragma unroll
        for (int f = 0; f < 8; ++f) sacc[f] = {0.f, 0.f, 0.f, 0.f};
        __builtin_amdgcn_s_setprio(1);
        #pragma unroll
        for (int ks = 0; ks < 2; ++ks) {
            #pragma unroll
            for (int f = 0; f < 8; ++f) {
                int arow = f * 16 + l15;          // j row in tile
                u32 aa = (u32)(arow * 128 + ks * 64 + g * 16);
                bf16x8 kf = *(const bf16x8*)(kb + (aa ^ ((arow & 7) << 4)));
                sacc[f] = __builtin_amdgcn_mfma_f32_16x16x32_bf16(kf, qf[ks], sacc[f], 0, 0, 0);
            }
        }
        __builtin_amdgcn_s_setprio(0);
        if (t == tD) {  // causal mask on the last tile only
            #pragma unroll
            for (int f = 0; f < 8; ++f)
                #pragma unroll
                for (int r = 0; r < 4; ++r)
                    if (f * 16 + g * 4 + r > delta + q_local) sacc[f][r] = -1e30f;
        }
        // ---- online softmax: 32 values/lane + xor16/xor32 ----
        float mx = -INFINITY;
        #pragma unroll
        for (int f = 0; f < 8; ++f) {
            float a = fmaxf(fmaxf(sacc[f][0], sacc[f][1]),
                            fmaxf(sacc[f][2], sacc[f][3]));
            mx = fmaxf(mx, a);
        }
        mx = fmaxf(mx, __shfl_xor(mx, 16));
        mx = fmaxf(mx, __shfl_xor(mx, 32));
        const float m_new = fmaxf(m_run, mx);
        const float alpha = __expf(m_run - m_new);
        float p[8][4];
        float ps = 0.f;
        #pragma unroll
        for (int f = 0; f < 8; ++f)
            #pragma unroll
            for (int r = 0; r < 4; ++r) {
                float pv = __expf(sacc[f][r] - m_new);
                p[f][r] = pv; ps += pv;
            }
        ps += __shfl_xor(ps, 16);
        ps += __shfl_xor(ps, 32);
        l_run = l_run * alpha + ps;
        m_run = m_new;
        #pragma unroll
        for (int nt = 0; nt < 4; ++nt)
            #pragma unroll
            for (int r = 0; r < 4; ++r) oacc[nt][r] *= alpha;

        // ---- P^T repack via per-wave LDS (same-wave, no barrier) ----
        #pragma unroll
        for (int f = 0; f < 8; ++f) {
            uint2 pk;
            pk.x = (u32)f2b(p[f][0]) | ((u32)f2b(p[f][1]) << 16);
            pk.y = (u32)f2b(p[f][2]) | ((u32)f2b(p[f][3]) << 16);
            u32 a = (u32)(l15 * 256 + f * 32 + g * 8) ^ pswz;
            *(uint2*)(pw + a) = pk;
        }
        bf16x8 pb_[4];
        #pragma unroll
        for (int ksj = 0; ksj < 4; ++ksj)
            pb_[ksj] = *(const bf16x8*)(pw + ((u32)(l15 * 256 + ksj * 64 + g * 16) ^ pswz));

        // ---- PV swapped: oacc[nt] += V[d][j] @ P^T[j][q], j = 0..127 ----
        __builtin_amdgcn_s_setprio(1);
        #pragma unroll
        for (int ksj = 0; ksj < 4; ++ksj) {
            #pragma unroll
            for (int nt = 0; nt < 4; ++nt) {
                int arow = nt * 16 + l15;          // d row
                u32 aa = (u32)(arow * 256 + ksj * 64 + g * 16);
                bf16x8 vf = *(const bf16x8*)(vb + (aa ^ ((arow & 15) << 4)));
                oacc[nt] = __builtin_amdgcn_mfma_f32_16x16x32_bf16(vf, pb_[ksj], oacc[nt], 0, 0, 0);
            }
        }
        __builtin_amdgcn_s_setprio(0);
        BAR();                                    // release cur
    }

    // write partials: O^T [d][q] bf16 (coalesced in l15), m/l per q
    const int slot = (b * 32 + qb) * SLOTS + chunk;
    u16* Op = pOt + (size_t)slot * 4096;
    #pragma unroll
    for (int nt = 0; nt < 4; ++nt)
        #pragma unroll
        for (int r = 0; r < 4; ++r)
            Op[(nt * 16 + g * 4 + r) * 64 + w * 16 + l15] = f2b(oacc[nt][r]);
    if (g == 0) {
        float* mlp = pml + (size_t)slot * 128;
        mlp[(w * 16 + l15) * 2]     = m_run;
        mlp[(w * 16 + l15) * 2 + 1] = l_run;
    }
}

// ---------------------------------------------------------------------------
// Merge <=SLOTS transposed partials per (b,qb); LDS transpose; fp32 out [q][d].
// grid = NB*32 blocks. nc matches attn decode.
// ---------------------------------------------------------------------------
__global__ __launch_bounds__(256) void merge(
    const u16* __restrict__ pOt, const float* __restrict__ pml,
    float* __restrict__ out)
{
    __shared__ float tl[64][65];
    const int bq = blockIdx.x;             // b*32 + qb
    const int b = bq >> 5, qb = bq & 31;
    const int nt128 = (qb + 2) >> 1;
    const int nc = (nt128 + CHUNK3 - 1) / CHUNK3;
    const int base = bq * SLOTS;
    const int q = threadIdx.x & 63, ds = threadIdx.x >> 6;

    float m = -INFINITY;
    for (int c = 0; c < nc; ++c)
        m = fmaxf(m, pml[(size_t)(base + c) * 128 + q * 2]);
    float lsum = 0.f;
    float acc[16];
    #pragma unroll
    for (int i = 0; i < 16; ++i) acc[i] = 0.f;
    for (int c = 0; c < nc; ++c) {
        const float mc = pml[(size_t)(base + c) * 128 + q * 2];
        const float lc = pml[(size_t)(base + c) * 128 + q * 2 + 1];
        const float wc = __expf(mc - m);
        lsum += wc * lc;
        const u16* Op = pOt + (size_t)(base + c) * 4096;
        #pragma unroll
        for (int i = 0; i < 16; ++i)
            acc[i] += wc * b2f(Op[(ds * 16 + i) * 64 + q]);
    }
    const float inv = 1.f / lsum;
    #pragma unroll
    for (int i = 0; i < 16; ++i) tl[q][ds * 16 + i] = acc[i] * inv;
    __syncthreads();
    const int q2 = threadIdx.x >> 2, dc = threadIdx.x & 3;
    float* orow = out + ((size_t)b * NT + qb * 64 + q2) * 64 + dc * 16;
    #pragma unroll
    for (int j4 = 0; j4 < 4; ++j4) {
        float4 v = { tl[q2][dc * 16 + j4 * 4 + 0], tl[q2][dc * 16 + j4 * 4 + 1],
                     tl[q2][dc * 16 + j4 * 4 + 2], tl[q2][dc * 16 + j4 * 4 + 3] };
        *(float4*)&orow[j4 * 4] = v;
    }
}

extern "C" void kernel_launch(void* const* d_in, const int* in_sizes, int n_in,
                              void* d_out, int out_size, void* d_ws, size_t ws_size,
                              hipStream_t stream) {
    const float* x  = (const float*)d_in[0];
    const float* WQ = (const float*)d_in[1];
    const float* WK = (const float*)d_in[2];
    const float* WV = (const float*)d_in[3];
    float* out = (float*)d_out;

    char* ws = (char*)d_ws;
    u16*   Qb  = (u16*)ws;                          // 1 MB
    u16*   Kb  = (u16*)(ws + 1048576);              // 1 MB
    u16*   Vt  = (u16*)(ws + 2097152);              // 1 MB
    u16*   Wt  = (u16*)(ws + 3145728);              // 384 KB
    u16*   pOt = (u16*)(ws + 3538944);              // 768 slots * 8 KB = 6 MB
    float* pml = (float*)(ws + 3538944 + 6291456);  // 384 KB

    // attn grid.x = sum over qb of ceil(((qb+2)>>1)/3) = 102
    wt_conv<<<dim3(16, 3), 256, 0, stream>>>(WQ, WK, WV, Wt);
    qkv_gemm<<<dim3(128, 3), 256, 0, stream>>>(x, Wt, Qb, Kb, Vt);
    attn<<<dim3(102, NB), 256, 0, stream>>>(Qb, Kb, Vt, pOt, pml);
    merge<<<NB * 32, 256, 0, stream>>>(pOt, pml, out);
}